// Round 7
// baseline (183.976 us; speedup 1.0000x reference)
//
#include <hip/hip_runtime.h>

#define NEG (-1e30f)

// Problem dims (fixed by setup_inputs): B=16, TXT=128, MEL=512, NM=80
#define B_   16
#define TXT_ 128
#define MEL_ 512
#define NM_  80
#define IT_  8     // i-rows per lp block

typedef float vf4 __attribute__((ext_vector_type(4)));

// ---------------------------------------------------------------------------
// Kernel 1: log_prob_matrix (unchanged from R6; correct since R3-fix).
// ---------------------------------------------------------------------------
__global__ __launch_bounds__(512) void lp_kernel(
    const float* __restrict__ mu_logvar,  // (B, TXT, 2*NM)
    const float* __restrict__ melspec,    // (B, NM, MEL)
    float* __restrict__ lp_out,           // (B, TXT, MEL)  = d_out + 1
    float* __restrict__ lp_ws,            // (B, TXT, MEL)  aligned copy in ws
    float* __restrict__ out0)             // d_out[0]
{
    const int i0 = blockIdx.x * IT_;
    const int b  = blockIdx.y;
    const int t  = threadIdx.x;

    __shared__ float2 s_wb[IT_][NM_];
    __shared__ float  s_cp[IT_ * NM_];
    __shared__ float  s_cc[IT_];

    for (int u = t; u < IT_ * NM_; u += 512) {
        int ii = u / NM_;
        int n  = u - ii * NM_;
        const float* row = mu_logvar + (size_t)(b * TXT_ + i0 + ii) * (2 * NM_);
        float mu = row[n];
        float lv = row[NM_ + n];
        float w  = __expf(-lv);
        s_wb[ii][n] = make_float2(w, -2.f * mu * w);
        s_cp[u]     = mu * mu * w + lv;
    }
    __syncthreads();
    if (t < IT_) {
        float c = 0.f;
        #pragma unroll
        for (int n = 0; n < NM_; ++n) c += s_cp[t * NM_ + n];
        s_cc[t] = c;
    }
    __syncthreads();

    const float* xcol = melspec + (size_t)b * NM_ * MEL_ + t;
    float acc[IT_];
    #pragma unroll
    for (int ii = 0; ii < IT_; ++ii) acc[ii] = 0.f;

    #pragma unroll 4
    for (int n = 0; n < NM_; ++n) {
        float x  = xcol[(size_t)n * MEL_];
        float x2 = x * x;
        #pragma unroll
        for (int ii = 0; ii < IT_; ++ii) {
            float2 wb = s_wb[ii][n];
            acc[ii] = fmaf(wb.x, x2, fmaf(wb.y, x, acc[ii]));
        }
    }

    const size_t rowbase = ((size_t)(b * TXT_ + i0)) * MEL_ + t;
    #pragma unroll
    for (int ii = 0; ii < IT_; ++ii) {
        float res = (-0.5f / (float)NM_) * (acc[ii] + s_cc[ii]);
        lp_out[rowbase + (size_t)ii * MEL_] = res;
        lp_ws [rowbase + (size_t)ii * MEL_] = res;
    }

    if (i0 == 0 && b == 0 && t == 0) *out0 = 0.f;
}

// ---------------------------------------------------------------------------
// Kernel 2: skewed-systolic scan, asm-pinned pipeline (R7).
// R3-R6 post-mortem: compiler sank every prefetch load to its consume
// (VGPR_Count 36 < the 47+ a live 8x float4 pipeline needs) and exposed
// ds_bpermute latency per step -> constant ~255-306 cyc/iter regardless of
// source-level buffering. This version pins the schedule with asm volatile:
//   - lane skew 8 (t = d - 8*l); lane owns cols j0=2l, j1=2l+1
//   - loads: asm global_load_dwordx4, 4 slot-pairs, refill 1 pair/group,
//     consume gated by s_waitcnt vmcnt(4) tied to the regs (3 pairs stay
//     in flight; data issued 12-16 steps before use)
//   - boundary: once per 4-step group, 4 back-to-back asm ds_bpermute of
//     the neighbor's a1-history (tail,pp0,pp1,pp2 = a1 after iters
//     d-5..d-2), consumed NEXT group behind one lgkmcnt(0) -> latency of
//     both issue batches fully overlapped with compute.
// Alignment proof: consume at iter d needs neighbor a1 after iter d-9;
// group start d0 issues history (d0-5..d0-2) which the NEXT group
// (iters d0+4..d0+7) consumes as (d+...-9) ✓. Warm-up NEG-init c/pp/tail
// supplies the "before step 1 = -inf" boundary exactly; -1e30+eps acts as
// exact -inf in laexp, so pre-start lanes never contaminate. Each lane
// snapshots its result exactly at t == Tend-1; overshoot steps are inert.
// ---------------------------------------------------------------------------
__device__ __forceinline__ float laexp(float a, float b) {
    float m = fmaxf(a, b);
    float d = fminf(a, b) - m;               // <= 0; exp underflows safely
    return m + __logf(1.f + __expf(d));
}

#define GLOAD(DST, PTR) \
    asm volatile("global_load_dwordx4 %0, %1, off" : "=v"(DST) : "v"(PTR))
#define VWAIT(A,B,C,D2) \
    asm volatile("s_waitcnt vmcnt(4)" : "+v"(A), "+v"(B), "+v"(C), "+v"(D2))
#define LWAIT(A,B,C,D2) \
    asm volatile("s_waitcnt lgkmcnt(0)" : "+v"(A), "+v"(B), "+v"(C), "+v"(D2))
#define BPERM(DST, SRC) \
    asm volatile("ds_bpermute_b32 %0, %1, %2" : "=v"(DST) : "v"(baddr), "v"(SRC))

__global__ __launch_bounds__(64) void scan_kernel(
    const float* __restrict__ lp,          // aligned copy (B, TXT, MEL)
    const int* __restrict__ text_len, const int* __restrict__ mel_len,
    float* __restrict__ out0)
{
    const int b = blockIdx.x;
    const int l = threadIdx.x;
    const float* base = lp + (size_t)b * TXT_ * MEL_;
    const int Tend = mel_len[b], TendM1 = Tend - 1;   // Tend in [256,512]

    const float* row0 = base + (size_t)(2 * l) * MEL_;   // j0 row (16B aligned)
    const float* row1 = row0 + MEL_;                     // j1 row
    const int baddr = 4 * max(l - 1, 0);                 // bpermute byte addr

    float a0 = (l == 0) ? base[0] : NEG;   // alpha[t][j0]
    float a1 = NEG;                        // alpha[t][j1]
    float fin0 = NEG, fin1 = NEG;

    int t_cur = 1 - 8 * l;                 // t at iteration d=1
    int t_pf  = 16 - 8 * l;                // next refill block start

    vf4 qa0, qa1, qb0, qb1, qc0, qc1, qd0, qd1;
    {
        int tc; const float *p0, *p1;
        tc = min(max(0 - 8 * l, 0), MEL_ - 4);
        p0 = row0 + tc; p1 = row1 + tc; GLOAD(qa0, p0); GLOAD(qa1, p1);
        tc = min(max(4 - 8 * l, 0), MEL_ - 4);
        p0 = row0 + tc; p1 = row1 + tc; GLOAD(qb0, p0); GLOAD(qb1, p1);
        tc = min(max(8 - 8 * l, 0), MEL_ - 4);
        p0 = row0 + tc; p1 = row1 + tc; GLOAD(qc0, p0); GLOAD(qc1, p1);
        tc = min(max(12 - 8 * l, 0), MEL_ - 4);
        p0 = row0 + tc; p1 = row1 + tc; GLOAD(qd0, p0); GLOAD(qd1, p1);
    }

    // boundary pipeline state (all NEG = "-inf before first step")
    float cx0 = NEG, cx1 = NEG, cx2 = NEG, cx3 = NEG;   // consume set A/C
    float ce0 = NEG, ce1 = NEG, ce2 = NEG, ce3 = NEG;   // consume set B/D
    float pp0 = NEG, pp1 = NEG, pp2 = NEG, pp3 = NEG;   // a1 hist (prev group)
    float tail = NEG;                                    // a1 hist (-5)
    float np0, np1, np2, np3;

    #define STEP(CIN, Q0, Q1, COMP, NP)                      \
        do {                                                 \
            float bnd = (l == 0) ? NEG : (CIN);              \
            float na0 = laexp(a0, bnd) + (Q0).COMP;          \
            float na1 = laexp(a1, a0)  + (Q1).COMP;          \
            bool hit = (t_cur == TendM1);                    \
            fin0 = hit ? na0 : fin0;                         \
            fin1 = hit ? na1 : fin1;                         \
            a0 = na0; a1 = na1; ++t_cur;                     \
            NP = na1;                                        \
        } while (0)

    #define REFILL(Q0, Q1)                                   \
        do {                                                 \
            int tc_ = min(max(t_pf, 0), MEL_ - 4);           \
            const float* p0_ = row0 + tc_;                   \
            const float* p1_ = row1 + tc_;                   \
            GLOAD(Q0, p0_); GLOAD(Q1, p1_);                  \
            t_pf += 4;                                       \
        } while (0)

    #define GROUP(C0,C1,C2,C3, E0,E1,E2,E3, QY0,QY1, QX0,QX1) \
        do {                                                 \
            VWAIT(QY0, QY1, QX0, QX1);                       \
            LWAIT(C0, C1, C2, C3);                           \
            BPERM(E0, tail); BPERM(E1, pp0);                 \
            BPERM(E2, pp1);  BPERM(E3, pp2);                 \
            tail = pp3;                                      \
            STEP(C0, QY0, QY1, y, np0);                      \
            STEP(C1, QY0, QY1, z, np1);                      \
            STEP(C2, QY0, QY1, w, np2);                      \
            REFILL(QY0, QY1);                                \
            STEP(C3, QX0, QX1, x, np3);                      \
            pp0 = np0; pp1 = np1; pp2 = np2; pp3 = np3;      \
        } while (0)

    const int D = TendM1 + 8 * 63;      // lane 63 hits t=TendM1 at iter D
    for (int d0 = 1; d0 <= D; d0 += 16) {
        GROUP(cx0,cx1,cx2,cx3, ce0,ce1,ce2,ce3, qa0,qa1, qb0,qb1);
        GROUP(ce0,ce1,ce2,ce3, cx0,cx1,cx2,cx3, qb0,qb1, qc0,qc1);
        GROUP(cx0,cx1,cx2,cx3, ce0,ce1,ce2,ce3, qc0,qc1, qd0,qd1);
        GROUP(ce0,ce1,ce2,ce3, cx0,cx1,cx2,cx3, qd0,qd1, qa0,qa1);
    }
    #undef STEP
    #undef REFILL
    #undef GROUP

    int jstar = text_len[b] - 1;                   // in [63,127]
    float v   = (jstar & 1) ? fin1 : fin0;
    float val = __shfl(v, jstar >> 1);
    if (l == 0) atomicAdd(out0, -(val / (float)Tend) * (1.f / (float)B_));
}

// ---------------------------------------------------------------------------
extern "C" void kernel_launch(void* const* d_in, const int* in_sizes, int n_in,
                              void* d_out, int out_size, void* d_ws, size_t ws_size,
                              hipStream_t stream) {
    const float* mu_logvar = (const float*)d_in[0];
    const float* melspec   = (const float*)d_in[1];
    const int*   text_len  = (const int*)d_in[2];
    const int*   mel_len   = (const int*)d_in[3];

    float* out    = (float*)d_out;      // out[0] = mdn_loss, out[1..] = lp
    float* lp_out = out + 1;
    float* lp_ws  = (float*)d_ws;       // 16B-aligned lp copy (4 MB)

    dim3 g1(TXT_ / IT_, B_);
    lp_kernel<<<g1, MEL_, 0, stream>>>(mu_logvar, melspec, lp_out, lp_ws, out);
    scan_kernel<<<B_, 64, 0, stream>>>(lp_ws, text_len, mel_len, out);
}

// Round 8
// 156.475 us; speedup vs baseline: 1.1758x; 1.1758x over previous
//
#include <hip/hip_runtime.h>

#define NEG (-1e30f)

// Problem dims (fixed by setup_inputs): B=16, TXT=128, MEL=512, NM=80
#define B_   16
#define TXT_ 128
#define MEL_ 512
#define NM_  80
#define IT_  8     // i-rows per lp block

typedef float vf4 __attribute__((ext_vector_type(4)));

// ---------------------------------------------------------------------------
// Kernel 1: log_prob_matrix (unchanged; correct since R3-fix).
// ---------------------------------------------------------------------------
__global__ __launch_bounds__(512) void lp_kernel(
    const float* __restrict__ mu_logvar,  // (B, TXT, 2*NM)
    const float* __restrict__ melspec,    // (B, NM, MEL)
    float* __restrict__ lp_out,           // (B, TXT, MEL)  = d_out + 1
    float* __restrict__ lp_ws,            // (B, TXT, MEL)  aligned copy in ws
    float* __restrict__ out0)             // d_out[0]
{
    const int i0 = blockIdx.x * IT_;
    const int b  = blockIdx.y;
    const int t  = threadIdx.x;

    __shared__ float2 s_wb[IT_][NM_];
    __shared__ float  s_cp[IT_ * NM_];
    __shared__ float  s_cc[IT_];

    for (int u = t; u < IT_ * NM_; u += 512) {
        int ii = u / NM_;
        int n  = u - ii * NM_;
        const float* row = mu_logvar + (size_t)(b * TXT_ + i0 + ii) * (2 * NM_);
        float mu = row[n];
        float lv = row[NM_ + n];
        float w  = __expf(-lv);
        s_wb[ii][n] = make_float2(w, -2.f * mu * w);
        s_cp[u]     = mu * mu * w + lv;
    }
    __syncthreads();
    if (t < IT_) {
        float c = 0.f;
        #pragma unroll
        for (int n = 0; n < NM_; ++n) c += s_cp[t * NM_ + n];
        s_cc[t] = c;
    }
    __syncthreads();

    const float* xcol = melspec + (size_t)b * NM_ * MEL_ + t;
    float acc[IT_];
    #pragma unroll
    for (int ii = 0; ii < IT_; ++ii) acc[ii] = 0.f;

    #pragma unroll 4
    for (int n = 0; n < NM_; ++n) {
        float x  = xcol[(size_t)n * MEL_];
        float x2 = x * x;
        #pragma unroll
        for (int ii = 0; ii < IT_; ++ii) {
            float2 wb = s_wb[ii][n];
            acc[ii] = fmaf(wb.x, x2, fmaf(wb.y, x, acc[ii]));
        }
    }

    const size_t rowbase = ((size_t)(b * TXT_ + i0)) * MEL_ + t;
    #pragma unroll
    for (int ii = 0; ii < IT_; ++ii) {
        float res = (-0.5f / (float)NM_) * (acc[ii] + s_cc[ii]);
        lp_out[rowbase + (size_t)ii * MEL_] = res;
        lp_ws [rowbase + (size_t)ii * MEL_] = res;
    }

    if (i0 == 0 && b == 0 && t == 0) *out0 = 0.f;
}

// ---------------------------------------------------------------------------
// Kernel 2: skewed-systolic scan (R8): DPP wave_shr1 boundary, NO LDS pipe.
// R3-R7 post-mortem: per-iter cost pinned at ~255-300 cyc across all load/
// buffer schedules; common factor was the per-step ds_bpermute (single-wave
// LDS-op latency ~120cyc, poor single-wave pipelining). This version moves
// the lane-boundary transfer to the VALU: v_mov_b32_dpp wave_shr:1 (0x138)
// == __shfl_up(a1,1) with lane0 taking `old` = NEG (exactly the boundary
// condition) -- no lgkmcnt, no LDS pipe, ~2cyc, and the l==0 select is free.
// Structure otherwise = R7 with skew 4 (763 iters): lane l owns cols j0=2l,
// j1=2l+1, computes t = d - 4l at iter d; 4 named float4 slot-pairs,
// asm global_load_dwordx4 refill 1 pair/4-step group, consume gated by
// s_waitcnt vmcnt(4) (3 pairs in flight, 12-16 step lead); 4-deep named
// delay ring r0..r3: rK written at iter d = neighbor a1 post-(d-1),
// consumed at iter d+4 needing post-((d+4)-5) ✓.
// Pre-start lanes stay ~NEG by induction; post-end garbage never consumed;
// each lane snapshots its result exactly at t == Tend-1.
// ---------------------------------------------------------------------------
__device__ __forceinline__ float laexp(float a, float b) {
    float m = fmaxf(a, b);
    float d = fminf(a, b) - m;               // <= 0; exp underflows safely
    return m + __logf(1.f + __expf(d));
}

// wave_shr:1 : lane l gets src from lane l-1; lane 0 keeps `old` (NEG).
__device__ __forceinline__ float dpp_shr1_neg(float src) {
    int o = __builtin_bit_cast(int, NEG);
    int s = __builtin_bit_cast(int, src);
    int r = __builtin_amdgcn_update_dpp(o, s, 0x138, 0xf, 0xf, false);
    return __builtin_bit_cast(float, r);
}

#define GLOAD(DST, PTR) \
    asm volatile("global_load_dwordx4 %0, %1, off" : "=v"(DST) : "v"(PTR))
#define VWAIT(A,B,C,D2) \
    asm volatile("s_waitcnt vmcnt(4)" : "+v"(A), "+v"(B), "+v"(C), "+v"(D2))

__global__ __launch_bounds__(64) void scan_kernel(
    const float* __restrict__ lp,          // aligned copy (B, TXT, MEL)
    const int* __restrict__ text_len, const int* __restrict__ mel_len,
    float* __restrict__ out0)
{
    const int b = blockIdx.x;
    const int l = threadIdx.x;
    const float* base = lp + (size_t)b * TXT_ * MEL_;
    const int Tend = mel_len[b], TendM1 = Tend - 1;   // Tend in [256,512]

    const float* row0 = base + (size_t)(2 * l) * MEL_;   // j0 row (16B aligned)
    const float* row1 = row0 + MEL_;                     // j1 row

    float a0 = (l == 0) ? base[0] : NEG;   // alpha[t][j0]
    float a1 = NEG;                        // alpha[t][j1]
    float fin0 = NEG, fin1 = NEG;

    int t_cur = 1 - 4 * l;                 // t at iteration d=1
    int t_pf  = 16 - 4 * l;                // next refill block start

    vf4 qa0, qa1, qb0, qb1, qc0, qc1, qd0, qd1;
    {
        int tc; const float *p0, *p1;
        tc = min(max(0 - 4 * l, 0), MEL_ - 4);
        p0 = row0 + tc; p1 = row1 + tc; GLOAD(qa0, p0); GLOAD(qa1, p1);
        tc = min(max(4 - 4 * l, 0), MEL_ - 4);
        p0 = row0 + tc; p1 = row1 + tc; GLOAD(qb0, p0); GLOAD(qb1, p1);
        tc = min(max(8 - 4 * l, 0), MEL_ - 4);
        p0 = row0 + tc; p1 = row1 + tc; GLOAD(qc0, p0); GLOAD(qc1, p1);
        tc = min(max(12 - 4 * l, 0), MEL_ - 4);
        p0 = row0 + tc; p1 = row1 + tc; GLOAD(qd0, p0); GLOAD(qd1, p1);
    }

    float r0 = NEG, r1 = NEG, r2 = NEG, r3 = NEG;   // boundary delay ring

    #define STEP(Q0, Q1, COMP, RREG)                         \
        do {                                                 \
            float bnd = RREG;                                \
            RREG = dpp_shr1_neg(a1);                         \
            float na0 = laexp(a0, bnd) + (Q0).COMP;          \
            float na1 = laexp(a1, a0)  + (Q1).COMP;          \
            bool hit = (t_cur == TendM1);                    \
            fin0 = hit ? na0 : fin0;                         \
            fin1 = hit ? na1 : fin1;                         \
            a0 = na0; a1 = na1; ++t_cur;                     \
        } while (0)

    #define REFILL(Q0, Q1)                                   \
        do {                                                 \
            int tc_ = min(max(t_pf, 0), MEL_ - 4);           \
            const float* p0_ = row0 + tc_;                   \
            const float* p1_ = row1 + tc_;                   \
            GLOAD(Q0, p0_); GLOAD(Q1, p1_);                  \
            t_pf += 4;                                       \
        } while (0)

    #define GROUP(QY0,QY1, QX0,QX1)                          \
        do {                                                 \
            VWAIT(QY0, QY1, QX0, QX1);                       \
            STEP(QY0, QY1, y, r1);                           \
            STEP(QY0, QY1, z, r2);                           \
            STEP(QY0, QY1, w, r3);                           \
            REFILL(QY0, QY1);                                \
            STEP(QX0, QX1, x, r0);                           \
        } while (0)

    const int D = TendM1 + 4 * 63;      // lane 63 hits t=TendM1 at iter D
    for (int d0 = 1; d0 <= D; d0 += 16) {
        GROUP(qa0,qa1, qb0,qb1);
        GROUP(qb0,qb1, qc0,qc1);
        GROUP(qc0,qc1, qd0,qd1);
        GROUP(qd0,qd1, qa0,qa1);
    }
    #undef STEP
    #undef REFILL
    #undef GROUP

    int jstar = text_len[b] - 1;                   // in [63,127]
    float v   = (jstar & 1) ? fin1 : fin0;
    float val = __shfl(v, jstar >> 1);
    if (l == 0) atomicAdd(out0, -(val / (float)Tend) * (1.f / (float)B_));
}

// ---------------------------------------------------------------------------
extern "C" void kernel_launch(void* const* d_in, const int* in_sizes, int n_in,
                              void* d_out, int out_size, void* d_ws, size_t ws_size,
                              hipStream_t stream) {
    const float* mu_logvar = (const float*)d_in[0];
    const float* melspec   = (const float*)d_in[1];
    const int*   text_len  = (const int*)d_in[2];
    const int*   mel_len   = (const int*)d_in[3];

    float* out    = (float*)d_out;      // out[0] = mdn_loss, out[1..] = lp
    float* lp_out = out + 1;
    float* lp_ws  = (float*)d_ws;       // 16B-aligned lp copy (4 MB)

    dim3 g1(TXT_ / IT_, B_);
    lp_kernel<<<g1, MEL_, 0, stream>>>(mu_logvar, melspec, lp_out, lp_ws, out);
    scan_kernel<<<B_, 64, 0, stream>>>(lp_ws, text_len, mel_len, out);
}

// Round 9
// 125.748 us; speedup vs baseline: 1.4631x; 1.2444x over previous
//
#include <hip/hip_runtime.h>

#define NEG (-1e30f)
#define LN2F 0.69314718056f

// Problem dims (fixed by setup_inputs): B=16, TXT=128, MEL=512, NM=80
#define B_   16
#define TXT_ 128
#define MEL_ 512
#define NM_  80
#define IT_  8     // i-rows per lp block

typedef float vf4 __attribute__((ext_vector_type(4)));

// ---------------------------------------------------------------------------
// Kernel 1: log_prob_matrix (structure proven since R3; lp_ws copy dropped --
// w_kernel now produces the scan's input).
// ---------------------------------------------------------------------------
__global__ __launch_bounds__(512) void lp_kernel(
    const float* __restrict__ mu_logvar,  // (B, TXT, 2*NM)
    const float* __restrict__ melspec,    // (B, NM, MEL)
    float* __restrict__ lp_out,           // (B, TXT, MEL)  = d_out + 1
    float* __restrict__ out0)             // d_out[0]
{
    const int i0 = blockIdx.x * IT_;
    const int b  = blockIdx.y;
    const int t  = threadIdx.x;

    __shared__ float2 s_wb[IT_][NM_];
    __shared__ float  s_cp[IT_ * NM_];
    __shared__ float  s_cc[IT_];

    for (int u = t; u < IT_ * NM_; u += 512) {   // 640 > 512: strided loop!
        int ii = u / NM_;
        int n  = u - ii * NM_;
        const float* row = mu_logvar + (size_t)(b * TXT_ + i0 + ii) * (2 * NM_);
        float mu = row[n];
        float lv = row[NM_ + n];
        float w  = __expf(-lv);
        s_wb[ii][n] = make_float2(w, -2.f * mu * w);
        s_cp[u]     = mu * mu * w + lv;
    }
    __syncthreads();
    if (t < IT_) {
        float c = 0.f;
        #pragma unroll
        for (int n = 0; n < NM_; ++n) c += s_cp[t * NM_ + n];
        s_cc[t] = c;
    }
    __syncthreads();

    const float* xcol = melspec + (size_t)b * NM_ * MEL_ + t;
    float acc[IT_];
    #pragma unroll
    for (int ii = 0; ii < IT_; ++ii) acc[ii] = 0.f;

    #pragma unroll 4
    for (int n = 0; n < NM_; ++n) {
        float x  = xcol[(size_t)n * MEL_];
        float x2 = x * x;
        #pragma unroll
        for (int ii = 0; ii < IT_; ++ii) {
            float2 wb = s_wb[ii][n];
            acc[ii] = fmaf(wb.x, x2, fmaf(wb.y, x, acc[ii]));
        }
    }

    const size_t rowbase = ((size_t)(b * TXT_ + i0)) * MEL_ + t;
    #pragma unroll
    for (int ii = 0; ii < IT_; ++ii) {
        lp_out[rowbase + (size_t)ii * MEL_] =
            (-0.5f / (float)NM_) * (acc[ii] + s_cc[ii]);
    }

    if (i0 == 0 && b == 0 && t == 0) *out0 = 0.f;
}

// ---------------------------------------------------------------------------
// Kernel 2 (NEW): w_kernel -- moves ALL transcendentals off the serial path.
//   mu[b][t]   = max_i lp[b][i][t]
//   w[b][i][t] = exp(lp[b][i][t] - mu - ln2)          (w <= 1/2)
//   musum[b]   = sum_{t=1..TendM1}(mu+ln2) + lp[b][0][0]
// musum is stashed in w[b][127][0] -- the one slot the scan loads but never
// consumes (t=0 column) -- so ws stays exactly 4 MB.
// One block per b: all (b,*) data local to the block -> clean ordering.
// ---------------------------------------------------------------------------
__global__ __launch_bounds__(512) void w_kernel(
    const float* __restrict__ lp,   // (B, TXT, MEL) = d_out + 1
    const int* __restrict__ mel_len,
    float* __restrict__ w)          // (B, TXT, MEL) in ws
{
    const int b = blockIdx.x;
    const int t = threadIdx.x;                       // mel frame
    const float* src = lp + (size_t)b * TXT_ * MEL_ + t;
    float* dstb = w + (size_t)b * TXT_ * MEL_;

    float m = NEG;
    #pragma unroll 8
    for (int i = 0; i < TXT_; ++i) m = fmaxf(m, src[(size_t)i * MEL_]);

    const float sh = m + LN2F;
    #pragma unroll 8
    for (int i = 0; i < TXT_; ++i)
        dstb[(size_t)i * MEL_ + t] = __expf(src[(size_t)i * MEL_] - sh);

    __shared__ float red[512];
    const int TendM1 = mel_len[b] - 1;
    red[t] = (t >= 1 && t <= TendM1) ? sh : 0.f;
    __syncthreads();
    #pragma unroll
    for (int s = 256; s > 0; s >>= 1) {
        if (t < s) red[t] += red[t + s];
        __syncthreads();
    }
    if (t == 0) {
        float lp00 = lp[(size_t)b * TXT_ * MEL_];
        dstb[(size_t)127 * MEL_] = red[0] + lp00;    // musum slot
    }
}

// ---------------------------------------------------------------------------
// Kernel 3: LINEAR-DOMAIN scan (R9). No skew, no transcendentals in-loop.
//   s[t][j] = (s[t-1][j] + s[t-1][j-1]) * w[t][j]
// Chain/step = DPP shr1 (VALU) + add + mul (~12 cyc) vs R8's 4 chained
// transcendentals (~252 cyc measured). alpha recovered at the end:
//   alpha[T][j] = log(s) + shift*ln2 + musum   (shift = exact p2 renorms)
// w <= 1/2 => s non-increasing (no overflow); every 16 steps a wave-uniform
// power-of-2 renorm (DPP max-reduce -> frexp) prevents underflow; scaling is
// exact, tracked in an int, so accuracy is unaffected.
// Load machinery = R8's proven 4-slot-pair asm global_load_dwordx4 +
// s_waitcnt vmcnt(4) gating, minus the skew offsets (all lanes share t).
// ---------------------------------------------------------------------------
__device__ __forceinline__ float dpp_shr1_zero(float x) {
    int r = __builtin_amdgcn_update_dpp(
        0, __builtin_bit_cast(int, x), 0x138 /*wave_shr:1*/, 0xf, 0xf, false);
    return __builtin_bit_cast(float, r);
}

#define DPPMAX(M, CTRL, RM)                                               \
    do {                                                                  \
        int _t = __builtin_amdgcn_update_dpp(                             \
            __builtin_bit_cast(int, M), __builtin_bit_cast(int, M),       \
            CTRL, RM, 0xf, false);                                        \
        M = fmaxf(M, __builtin_bit_cast(float, _t));                      \
    } while (0)

#define GLOAD(DST, PTR) \
    asm volatile("global_load_dwordx4 %0, %1, off" : "=v"(DST) : "v"(PTR))
#define VWAIT(A,B,C,D2) \
    asm volatile("s_waitcnt vmcnt(4)" : "+v"(A), "+v"(B), "+v"(C), "+v"(D2))

__global__ __launch_bounds__(64) void scan_kernel(
    const float* __restrict__ w,           // (B, TXT, MEL) in ws
    const int* __restrict__ text_len, const int* __restrict__ mel_len,
    float* __restrict__ out0)
{
    const int b = blockIdx.x;
    const int l = threadIdx.x;
    const float* base = w + (size_t)b * TXT_ * MEL_;
    const int Tend = mel_len[b], TendM1 = Tend - 1;   // Tend in [256,512]

    const float* row0 = base + (size_t)(2 * l) * MEL_;   // j0 row (16B aligned)
    const float* row1 = row0 + MEL_;                     // j1 row

    const float musum = base[(size_t)127 * MEL_];        // stashed constant

    float s0 = (l == 0) ? 1.f : 0.f;   // s[t][j0]; 0 == "-inf"
    float s1 = 0.f;                    // s[t][j1]
    float fin0 = 0.f, fin1 = 0.f;
    int   shift_acc = 0, fsh = 0;

    int t_cur = 1;
    int t_pf  = 16;

    vf4 qa0, qa1, qb0, qb1, qc0, qc1, qd0, qd1;
    {
        const float *p0, *p1;
        p0 = row0 + 0;  p1 = row1 + 0;  GLOAD(qa0, p0); GLOAD(qa1, p1);
        p0 = row0 + 4;  p1 = row1 + 4;  GLOAD(qb0, p0); GLOAD(qb1, p1);
        p0 = row0 + 8;  p1 = row1 + 8;  GLOAD(qc0, p0); GLOAD(qc1, p1);
        p0 = row0 + 12; p1 = row1 + 12; GLOAD(qd0, p0); GLOAD(qd1, p1);
    }

    #define STEP(Q0, Q1, COMP)                               \
        do {                                                 \
            float nb  = dpp_shr1_zero(s1);                   \
            float ns0 = (s0 + nb) * (Q0).COMP;               \
            float ns1 = (s1 + s0) * (Q1).COMP;               \
            bool hit = (t_cur == TendM1);                    \
            fin0 = hit ? ns0 : fin0;                         \
            fin1 = hit ? ns1 : fin1;                         \
            fsh  = hit ? shift_acc : fsh;                    \
            s0 = ns0; s1 = ns1; ++t_cur;                     \
        } while (0)

    #define REFILL(Q0, Q1)                                   \
        do {                                                 \
            int tc_ = min(t_pf, MEL_ - 4);                   \
            const float* p0_ = row0 + tc_;                   \
            const float* p1_ = row1 + tc_;                   \
            GLOAD(Q0, p0_); GLOAD(Q1, p1_);                  \
            t_pf += 4;                                       \
        } while (0)

    #define GROUP(QY0,QY1, QX0,QX1)                          \
        do {                                                 \
            VWAIT(QY0, QY1, QX0, QX1);                       \
            STEP(QY0, QY1, y);                               \
            STEP(QY0, QY1, z);                               \
            STEP(QY0, QY1, w);                               \
            REFILL(QY0, QY1);                                \
            STEP(QX0, QX1, x);                               \
        } while (0)

    for (int t0 = 1; t0 <= TendM1; t0 += 16) {
        GROUP(qa0,qa1, qb0,qb1);
        GROUP(qb0,qb1, qc0,qc1);
        GROUP(qc0,qc1, qd0,qd1);
        GROUP(qd0,qd1, qa0,qa1);

        // exact power-of-2 renorm (wave-uniform; factor exactness means any
        // reduce imprecision only affects range safety, never the result)
        float mm = fmaxf(s0, s1);
        DPPMAX(mm, 0x111, 0xf);   // row_shr:1
        DPPMAX(mm, 0x112, 0xf);   // row_shr:2
        DPPMAX(mm, 0x114, 0xf);   // row_shr:4
        DPPMAX(mm, 0x118, 0xf);   // row_shr:8
        DPPMAX(mm, 0x142, 0xa);   // row_bcast:15 -> rows 1,3
        DPPMAX(mm, 0x143, 0xc);   // row_bcast:31 -> rows 2,3
        float M = __builtin_bit_cast(
            float, __builtin_amdgcn_readlane(__builtin_bit_cast(int, mm), 63));
        if (M > 0.f) {
            int e;
            (void)frexpf(M, &e);
            float sc = ldexpf(1.f, -e);
            s0 *= sc; s1 *= sc;
            shift_acc += e;
        }
    }
    #undef STEP
    #undef REFILL
    #undef GROUP

    int jstar = text_len[b] - 1;                   // in [63,127]
    float vs = (jstar & 1) ? fin1 : fin0;
    int   vh = (jstar & 1) ? fsh  : fsh;           // same reg; shfl below picks lane
    vs = __shfl(vs, jstar >> 1);
    vh = __shfl(vh, jstar >> 1);
    if (l == 0) {
        float val = __logf(vs) + (float)vh * LN2F + musum;
        atomicAdd(out0, -(val / (float)Tend) * (1.f / (float)B_));
    }
}

// ---------------------------------------------------------------------------
extern "C" void kernel_launch(void* const* d_in, const int* in_sizes, int n_in,
                              void* d_out, int out_size, void* d_ws, size_t ws_size,
                              hipStream_t stream) {
    const float* mu_logvar = (const float*)d_in[0];
    const float* melspec   = (const float*)d_in[1];
    const int*   text_len  = (const int*)d_in[2];
    const int*   mel_len   = (const int*)d_in[3];

    float* out    = (float*)d_out;      // out[0] = mdn_loss, out[1..] = lp
    float* lp_out = out + 1;
    float* w_ws   = (float*)d_ws;       // 4 MB exp-domain weights

    dim3 g1(TXT_ / IT_, B_);
    lp_kernel<<<g1, MEL_, 0, stream>>>(mu_logvar, melspec, lp_out, out);
    w_kernel<<<B_, MEL_, 0, stream>>>(lp_out, mel_len, w_ws);
    scan_kernel<<<B_, 64, 0, stream>>>(w_ws, text_len, mel_len, out);
}

// Round 11
// 102.308 us; speedup vs baseline: 1.7983x; 1.2291x over previous
//
#include <hip/hip_runtime.h>

#define NEG  (-1e30f)
#define LN2F 0.69314718056f

// Problem dims (fixed by setup_inputs): B=16, TXT=128, MEL=512, NM=80
#define B_   16
#define TXT_ 128
#define MEL_ 512
#define NM_  80
#define IT_  8     // i-rows per lp block

typedef float vf2 __attribute__((ext_vector_type(2)));

// ---------------------------------------------------------------------------
// Kernel 1: log_prob_matrix (proven since R3). Also zeroes out[0] and the
// per-b musum stash wT[b][0][0] (wt_kernel atomicAdds into it later).
// ---------------------------------------------------------------------------
__global__ __launch_bounds__(512) void lp_kernel(
    const float* __restrict__ mu_logvar,  // (B, TXT, 2*NM)
    const float* __restrict__ melspec,    // (B, NM, MEL)
    float* __restrict__ lp_out,           // (B, TXT, MEL)  = d_out + 1
    float* __restrict__ wT,               // (B, MEL, TXT) in ws (stash zero)
    float* __restrict__ out0)             // d_out[0]
{
    const int i0 = blockIdx.x * IT_;
    const int b  = blockIdx.y;
    const int t  = threadIdx.x;

    __shared__ float2 s_wb[IT_][NM_];
    __shared__ float  s_cp[IT_ * NM_];
    __shared__ float  s_cc[IT_];

    for (int u = t; u < IT_ * NM_; u += 512) {   // 640 > 512: strided loop!
        int ii = u / NM_;
        int n  = u - ii * NM_;
        const float* row = mu_logvar + (size_t)(b * TXT_ + i0 + ii) * (2 * NM_);
        float mu = row[n];
        float lv = row[NM_ + n];
        float w  = __expf(-lv);
        s_wb[ii][n] = make_float2(w, -2.f * mu * w);
        s_cp[u]     = mu * mu * w + lv;
    }
    __syncthreads();
    if (t < IT_) {
        float c = 0.f;
        #pragma unroll
        for (int n = 0; n < NM_; ++n) c += s_cp[t * NM_ + n];
        s_cc[t] = c;
    }
    __syncthreads();

    const float* xcol = melspec + (size_t)b * NM_ * MEL_ + t;
    float acc[IT_];
    #pragma unroll
    for (int ii = 0; ii < IT_; ++ii) acc[ii] = 0.f;

    #pragma unroll 4
    for (int n = 0; n < NM_; ++n) {
        float x  = xcol[(size_t)n * MEL_];
        float x2 = x * x;
        #pragma unroll
        for (int ii = 0; ii < IT_; ++ii) {
            float2 wb = s_wb[ii][n];
            acc[ii] = fmaf(wb.x, x2, fmaf(wb.y, x, acc[ii]));
        }
    }

    const size_t rowbase = ((size_t)(b * TXT_ + i0)) * MEL_ + t;
    #pragma unroll
    for (int ii = 0; ii < IT_; ++ii) {
        lp_out[rowbase + (size_t)ii * MEL_] =
            (-0.5f / (float)NM_) * (acc[ii] + s_cc[ii]);
    }

    if (i0 == 0 && t == 0) wT[(size_t)b * MEL_ * TXT_] = 0.f;  // stash = 0
    if (i0 == 0 && b == 0 && t == 0) *out0 = 0.f;
}

// ---------------------------------------------------------------------------
// Kernel 2: fused shift + exp + transpose (R11).
//   mu_t = max_i lp[b][i][t];  wT[b][t][i] = exp(lp[b][i][t] - mu_t - ln2)
//   stash wT[b][0][0] += sum_{t in [1,TendM1]}(mu_t+ln2)  (+ lp00 from t0=0)
// The mu-shift is LOAD-BEARING (R10 post-mortem): w <= 1/2 keeps the max
// column's per-step factor ~1, so lagging columns never hit flush-to-zero
// between the scan's renorms. Block = 128x32 (i x t) LDS slab; reads and
// writes both coalesced; global row t=0 of wT is left as the stash row
// (scan only reads rows 1..511).
// ---------------------------------------------------------------------------
__global__ __launch_bounds__(256) void wt_kernel(
    const float* __restrict__ lp,   // (B, TXT, MEL) = d_out + 1
    const int* __restrict__ mel_len,
    float* __restrict__ wT)         // (B, MEL, TXT) in ws
{
    __shared__ float tileT[32][TXT_ + 1];   // [t_loc][i], pad breaks conflicts
    __shared__ float pmax[32][8];
    __shared__ float psum[32];

    const int t0  = blockIdx.x * 32;   // mel tile
    const int b   = blockIdx.y;
    const int tid = threadIdx.x;       // 0..255

    const float* src = lp + (size_t)b * TXT_ * MEL_ + t0;
    for (int u = tid; u < TXT_ * 32; u += 256) {
        int i = u >> 5, c = u & 31;
        tileT[c][i] = src[(size_t)i * MEL_ + c];
    }
    __syncthreads();

    {   // 8-way partial max over i per t_loc
        int tt = tid >> 3, g = tid & 7;
        float m = NEG;
        #pragma unroll
        for (int k = 0; k < 16; ++k) m = fmaxf(m, tileT[tt][g * 16 + k]);
        pmax[tt][g] = m;
    }
    __syncthreads();
    if (tid < 32) {
        float m = pmax[tid][0];
        #pragma unroll
        for (int g = 1; g < 8; ++g) m = fmaxf(m, pmax[tid][g]);
        pmax[tid][0] = m;                          // mu_t
        int tg = t0 + tid;
        int TendM1 = mel_len[b] - 1;
        psum[tid] = (tg >= 1 && tg <= TendM1) ? (m + LN2F) : 0.f;
    }
    __syncthreads();

    float* dstb = wT + (size_t)b * MEL_ * TXT_;
    for (int u = tid; u < 32 * TXT_; u += 256) {
        int tt = u >> 7, i = u & 127;
        int tg = t0 + tt;
        if (tg != 0)   // keep global row 0 as the stash row
            dstb[(size_t)tg * TXT_ + i] =
                __expf(tileT[tt][i] - pmax[tt][0] - LN2F);
    }

    if (tid == 0) {
        float s = 0.f;
        #pragma unroll
        for (int k = 0; k < 32; ++k) s += psum[k];
        if (t0 == 0) s += tileT[0][0];             // + lp[b][0][0]
        atomicAdd(&dstb[0], s);                    // musum stash
    }
}

// ---------------------------------------------------------------------------
// Kernel 3: linear-domain scan (R10 machinery + R9 numerics).
//   s[t][j] = (s[t-1][j] + s[t-1][j-1]) * w[t][j],  w <= 1/2 (pre-exp'd!)
// Lane l owns cols j0=2l, j1=2l+1. Chain/step = DPP wave_shr1 + add + mul;
// NO transcendentals in-loop at all now. Coalesced global_load_dwordx2 per
// lane per step through 16 named slots gated by s_waitcnt vmcnt(12)
// (~16-step lead). Exact p2 renorm every 16 steps; alpha recovered as
// log(s) + shift*ln2 + musum (musum from the wt_kernel stash).
// ---------------------------------------------------------------------------
__device__ __forceinline__ float dpp_shr1_zero(float x) {
    int r = __builtin_amdgcn_update_dpp(
        0, __builtin_bit_cast(int, x), 0x138 /*wave_shr:1*/, 0xf, 0xf, false);
    return __builtin_bit_cast(float, r);
}

#define DPPMAX(M, CTRL, RM)                                               \
    do {                                                                  \
        int _t = __builtin_amdgcn_update_dpp(                             \
            __builtin_bit_cast(int, M), __builtin_bit_cast(int, M),       \
            CTRL, RM, 0xf, false);                                        \
        M = fmaxf(M, __builtin_bit_cast(float, _t));                      \
    } while (0)

#define GLOAD2(DST, PTR) \
    asm volatile("global_load_dwordx2 %0, %1, off" : "=v"(DST) : "v"(PTR))
#define VWAIT12(A,B,C,D2) \
    asm volatile("s_waitcnt vmcnt(12)" : "+v"(A), "+v"(B), "+v"(C), "+v"(D2))

__global__ __launch_bounds__(64) void scan_kernel(
    const float* __restrict__ wT,          // (B, MEL, TXT) in ws
    const int* __restrict__ text_len, const int* __restrict__ mel_len,
    float* __restrict__ out0)
{
    const int b = blockIdx.x;
    const int l = threadIdx.x;
    const float* base = wT + (size_t)b * MEL_ * TXT_;
    const float* wb_  = base + 2 * l;                 // lane column ptr
    const int Tend = mel_len[b], TendM1 = Tend - 1;   // Tend in [256,512]

    float s0 = (l == 0) ? 1.f : 0.f;   // s[t][j0]
    float s1 = 0.f;                    // s[t][j1]
    float fin0 = 0.f, fin1 = 0.f;
    int   shift_acc = 0, fsh = 0;
    int   t_cur = 1;
    int   t_pf  = 17;                  // next refill row

    vf2 q0,q1,q2,q3,q4,q5,q6,q7,q8,q9,q10,q11,q12,q13,q14,q15;
    {
        const float* p;
        #define INIT(Q, ROW) p = wb_ + (size_t)(ROW) * TXT_; GLOAD2(Q, p)
        INIT(q0,1);  INIT(q1,2);  INIT(q2,3);   INIT(q3,4);
        INIT(q4,5);  INIT(q5,6);  INIT(q6,7);   INIT(q7,8);
        INIT(q8,9);  INIT(q9,10); INIT(q10,11); INIT(q11,12);
        INIT(q12,13); INIT(q13,14); INIT(q14,15); INIT(q15,16);
        #undef INIT
    }

    #define STEP(Q)                                          \
        do {                                                 \
            float nb  = dpp_shr1_zero(s1);                   \
            float ns0 = (s0 + nb) * (Q).x;                   \
            float ns1 = (s1 + s0) * (Q).y;                   \
            bool hit = (t_cur == TendM1);                    \
            fin0 = hit ? ns0 : fin0;                         \
            fin1 = hit ? ns1 : fin1;                         \
            fsh  = hit ? shift_acc : fsh;                    \
            s0 = ns0; s1 = ns1; ++t_cur;                     \
        } while (0)

    #define REFILL(Q)                                        \
        do {                                                 \
            int rr = min(t_pf, MEL_ - 1);                    \
            const float* p_ = wb_ + (size_t)rr * TXT_;       \
            GLOAD2(Q, p_);                                   \
            ++t_pf;                                          \
        } while (0)

    #define GROUP(QA,QB,QC,QD)                               \
        do {                                                 \
            VWAIT12(QA,QB,QC,QD);                            \
            STEP(QA); STEP(QB); STEP(QC); STEP(QD);          \
            REFILL(QA); REFILL(QB); REFILL(QC); REFILL(QD);  \
        } while (0)

    for (int t0 = 1; t0 <= TendM1; t0 += 16) {
        GROUP(q0,q1,q2,q3);
        GROUP(q4,q5,q6,q7);
        GROUP(q8,q9,q10,q11);
        GROUP(q12,q13,q14,q15);

        // exact power-of-2 renorm (wave-uniform)
        float mm = fmaxf(s0, s1);
        DPPMAX(mm, 0x111, 0xf);   // row_shr:1
        DPPMAX(mm, 0x112, 0xf);   // row_shr:2
        DPPMAX(mm, 0x114, 0xf);   // row_shr:4
        DPPMAX(mm, 0x118, 0xf);   // row_shr:8
        DPPMAX(mm, 0x142, 0xa);   // row_bcast:15 -> rows 1,3
        DPPMAX(mm, 0x143, 0xc);   // row_bcast:31 -> rows 2,3
        float M = __builtin_bit_cast(
            float, __builtin_amdgcn_readlane(__builtin_bit_cast(int, mm), 63));
        if (M > 0.f) {
            int e;
            (void)frexpf(M, &e);
            float sc = ldexpf(1.f, -e);
            s0 *= sc; s1 *= sc;
            shift_acc += e;
        }
    }
    #undef STEP
    #undef REFILL
    #undef GROUP

    int jstar = text_len[b] - 1;                   // in [63,127]
    float vs = (jstar & 1) ? fin1 : fin0;
    int   vh = fsh;
    vs = __shfl(vs, jstar >> 1);
    vh = __shfl(vh, jstar >> 1);
    if (l == 0) {
        float musum = base[0];                     // wt_kernel stash
        float val   = __logf(vs) + (float)vh * LN2F + musum;
        atomicAdd(out0, -(val / (float)Tend) * (1.f / (float)B_));
    }
}

// ---------------------------------------------------------------------------
extern "C" void kernel_launch(void* const* d_in, const int* in_sizes, int n_in,
                              void* d_out, int out_size, void* d_ws, size_t ws_size,
                              hipStream_t stream) {
    const float* mu_logvar = (const float*)d_in[0];
    const float* melspec   = (const float*)d_in[1];
    const int*   text_len  = (const int*)d_in[2];
    const int*   mel_len   = (const int*)d_in[3];

    float* out    = (float*)d_out;      // out[0] = mdn_loss, out[1..] = lp
    float* lp_out = out + 1;
    float* wT     = (float*)d_ws;       // 4 MB transposed shifted-exp weights

    dim3 g1(TXT_ / IT_, B_);
    lp_kernel<<<g1, MEL_, 0, stream>>>(mu_logvar, melspec, lp_out, wT, out);
    dim3 g2(MEL_ / 32, B_);
    wt_kernel<<<g2, 256, 0, stream>>>(lp_out, mel_len, wT);
    scan_kernel<<<B_, 64, 0, stream>>>(wT, text_len, mel_len, out);
}